// Round 5
// baseline (249.229 us; speedup 1.0000x reference)
//
#include <hip/hip_runtime.h>
#include <cstdint>
#include <cstddef>

#define D_DIM   256
#define B_ROWS  1024
#define C_CLS   200000
#define S_SC    64.0f
#define COS_M_F 0.87758256189037271612f
#define SIN_M_F 0.47942553860420300027f
#define EPS_F   1e-8f

#define BM 256
#define BN 256
#define BK2 32                     /* K chunk */
#define NKT 8                      /* 256/32 K-tiles */
#define NTN 782                    /* N-tiles: 782*256 = 200192 */
#define CPAD (NTN * BN)            /* 200192 */
#define NBLK (4 * NTN)             /* 3128 = 8*391 */

typedef short bf16x8 __attribute__((ext_vector_type(8)));
typedef float f32x4  __attribute__((ext_vector_type(4)));

__device__ __forceinline__ unsigned short f2bf(float x) {
  unsigned int u = __builtin_bit_cast(unsigned int, x);
  return (unsigned short)((u + 0x8000u) >> 16);
}
__device__ __forceinline__ float bf2f(unsigned short u) {
  return __builtin_bit_cast(float, ((unsigned int)u) << 16);
}

// ---------------- kernel 1: normalize embeddings -> bf16 in ws ----------------
__global__ void k_norm_embed(const float* __restrict__ emb,
                             unsigned short* __restrict__ ebf) {
  int wid = threadIdx.x >> 6, lane = threadIdx.x & 63;
  int row = (blockIdx.x << 2) + wid;
  const float4 v = *reinterpret_cast<const float4*>(emb + (size_t)row * D_DIM + lane * 4);
  float ss = v.x * v.x + v.y * v.y + v.z * v.z + v.w * v.w;
#pragma unroll
  for (int m = 32; m >= 1; m >>= 1) ss += __shfl_xor(ss, m, 64);
  float inv = 1.0f / fmaxf(sqrtf(ss), 1e-12f);
  ushort4 o;
  o.x = f2bf(v.x * inv); o.y = f2bf(v.y * inv);
  o.z = f2bf(v.z * inv); o.w = f2bf(v.w * inv);
  *reinterpret_cast<ushort4*>(ebf + (size_t)row * D_DIM + lane * 4) = o;
}

// ---------------- kernel 2: normalize prototypes -> bf16, zero-pad ------------
__global__ void k_proto_norm_cvt(const float* __restrict__ proto,
                                 unsigned short* __restrict__ pbf) {
  int wid = threadIdx.x >> 6, lane = threadIdx.x & 63;
  int row = (blockIdx.x << 2) + wid;               // grid = CPAD/4
  if (row >= C_CLS) {
    *reinterpret_cast<ushort4*>(pbf + (size_t)row * D_DIM + lane * 4) =
        (ushort4){0, 0, 0, 0};
    return;
  }
  const float4 v = *reinterpret_cast<const float4*>(proto + (size_t)row * D_DIM + lane * 4);
  float ss = v.x * v.x + v.y * v.y + v.z * v.z + v.w * v.w;
#pragma unroll
  for (int m = 32; m >= 1; m >>= 1) ss += __shfl_xor(ss, m, 64);
  float inv = 1.0f / fmaxf(sqrtf(ss), 1e-12f);
  ushort4 o;
  o.x = f2bf(v.x * inv); o.y = f2bf(v.y * inv);
  o.z = f2bf(v.z * inv); o.w = f2bf(v.w * inv);
  *reinterpret_cast<ushort4*>(pbf + (size_t)row * D_DIM + lane * 4) = o;
}

// ---------------- kernel 3: 8-phase counted-vmcnt GEMM + exp + row-sum --------
// 256x256 tile, BK=32, 3-deep K-tile ring, 8 waves (2Mx4N), 16 phases.
// Per tile: 2 phases x {stage half | ds_read frags | barrier | 16 MFMA | barrier},
// tile boundary waits s_waitcnt vmcnt(4) (counted, never 0 in steady state).
__global__ __launch_bounds__(512, 2) void k_gemm_8ph(
    const unsigned short* __restrict__ ebf, const unsigned short* __restrict__ pbf,
    float* __restrict__ sums) {
  __shared__ __align__(16) short As[3][BM * BK2];   // 3 x 16 KiB
  __shared__ __align__(16) short Bs[3][BN * BK2];   // 3 x 16 KiB
  __shared__ float rowsum[BM];

  const int t = threadIdx.x;
  const int lane = t & 63;
  const int W = t >> 6;             // wave 0..7
  const int wm = W >> 2;            // 0..1 : M strip of 128
  const int wn = W & 3;             // 0..3 : N strip of 64

  int bid = (int)blockIdx.x;
  int w = (bid & 7) * (NBLK / 8) + (bid >> 3);   // bijective XCD swizzle
  const int ntile = w >> 2;
  const int mtile = w & 3;
  const int m0 = mtile * BM;
  const int n0 = ntile * BN;

  if (t < BM) rowsum[t] = 0.0f;

  f32x4 acc[8][4];
  const f32x4 fz = {0.0f, 0.0f, 0.0f, 0.0f};
#pragma unroll
  for (int mi = 0; mi < 8; ++mi)
#pragma unroll
    for (int ni = 0; ni < 4; ++ni) acc[mi][ni] = fz;

  // staging geometry: idx = j*512 + t ; cell row r = idx>>2, phys slot p = idx&3,
  // logical k-slot sl = (p ^ r) & 3  (pre-swizzled global source, linear LDS dest)
  const int r0 = t >> 2,        r1 = 128 + (t >> 2);
  const int p0 = t & 3;
  const int sl0 = (p0 ^ r0) & 3, sl1 = (p0 ^ r1) & 3;   // note r1 = r0+128: same low bits
  const int dst0 = t * 8, dst1 = (512 + t) * 8;

  auto stageA = [&](int s, int kt) {
    const int k0 = kt * BK2;
    const unsigned short* g0 = ebf + (size_t)(m0 + r0) * D_DIM + k0 + sl0 * 8;
    __builtin_amdgcn_global_load_lds(
        (const __attribute__((address_space(1))) unsigned int*)(const void*)g0,
        (__attribute__((address_space(3))) unsigned int*)(void*)(&As[s][dst0]), 16, 0, 0);
    const unsigned short* g1 = ebf + (size_t)(m0 + r1) * D_DIM + k0 + sl1 * 8;
    __builtin_amdgcn_global_load_lds(
        (const __attribute__((address_space(1))) unsigned int*)(const void*)g1,
        (__attribute__((address_space(3))) unsigned int*)(void*)(&As[s][dst1]), 16, 0, 0);
  };
  auto stageB = [&](int s, int kt) {
    const int k0 = kt * BK2;
    const unsigned short* g0 = pbf + (size_t)(n0 + r0) * D_DIM + k0 + sl0 * 8;
    __builtin_amdgcn_global_load_lds(
        (const __attribute__((address_space(1))) unsigned int*)(const void*)g0,
        (__attribute__((address_space(3))) unsigned int*)(void*)(&Bs[s][dst0]), 16, 0, 0);
    const unsigned short* g1 = pbf + (size_t)(n0 + r1) * D_DIM + k0 + sl1 * 8;
    __builtin_amdgcn_global_load_lds(
        (const __attribute__((address_space(1))) unsigned int*)(const void*)g1,
        (__attribute__((address_space(3))) unsigned int*)(void*)(&Bs[s][dst1]), 16, 0, 0);
  };

  const int sl_rd = lane >> 4;           // logical k-slot this lane reads
  auto readA = [&](int s, int r) -> bf16x8 {
    int phys = (sl_rd ^ r) & 3;
    return *reinterpret_cast<const bf16x8*>(&As[s][r * BK2 + phys * 8]);
  };
  auto readB = [&](int s, int r) -> bf16x8 {
    int phys = (sl_rd ^ r) & 3;
    return *reinterpret_cast<const bf16x8*>(&Bs[s][r * BK2 + phys * 8]);
  };

  // ---- prologue: stage T0, T1; wait T0; barrier ----
  stageA(0, 0); stageB(0, 0);
  stageA(1, 1); stageB(1, 1);
  asm volatile("s_waitcnt vmcnt(4)" ::: "memory");
  __builtin_amdgcn_sched_barrier(0);
  __builtin_amdgcn_s_barrier();
  __builtin_amdgcn_sched_barrier(0);

#pragma unroll
  for (int tt = 0; tt < NKT; ++tt) {
    const int s = tt % 3;
    bf16x8 bfv[4];
    // ---------------- phase 0: Mq=0, all N frags ----------------
    if (tt + 2 < NKT) stageA((tt + 2) % 3, tt + 2);
    bf16x8 af[4];
#pragma unroll
    for (int mi = 0; mi < 4; ++mi)
      af[mi] = readA(s, wm * 128 + mi * 16 + (lane & 15));
#pragma unroll
    for (int ni = 0; ni < 4; ++ni)
      bfv[ni] = readB(s, wn * 64 + ni * 16 + (lane & 15));
    __builtin_amdgcn_sched_barrier(0);
    __builtin_amdgcn_s_barrier();
    __builtin_amdgcn_sched_barrier(0);
    __builtin_amdgcn_s_setprio(1);
#pragma unroll
    for (int mi = 0; mi < 4; ++mi)
#pragma unroll
      for (int ni = 0; ni < 4; ++ni)
        acc[mi][ni] = __builtin_amdgcn_mfma_f32_16x16x32_bf16(
            af[mi], bfv[ni], acc[mi][ni], 0, 0, 0);
    __builtin_amdgcn_s_setprio(0);
    __builtin_amdgcn_sched_barrier(0);
    __builtin_amdgcn_s_barrier();
    __builtin_amdgcn_sched_barrier(0);
    // ---------------- phase 1: Mq=1, reuse B frags ----------------
    if (tt + 2 < NKT) stageB((tt + 2) % 3, tt + 2);
#pragma unroll
    for (int mi = 0; mi < 4; ++mi)
      af[mi] = readA(s, wm * 128 + (mi + 4) * 16 + (lane & 15));
    __builtin_amdgcn_sched_barrier(0);
    __builtin_amdgcn_s_barrier();
    __builtin_amdgcn_sched_barrier(0);
    __builtin_amdgcn_s_setprio(1);
#pragma unroll
    for (int mi = 0; mi < 4; ++mi)
#pragma unroll
      for (int ni = 0; ni < 4; ++ni)
        acc[mi + 4][ni] = __builtin_amdgcn_mfma_f32_16x16x32_bf16(
            af[mi], bfv[ni], acc[mi + 4][ni], 0, 0, 0);
    __builtin_amdgcn_s_setprio(0);
    __builtin_amdgcn_sched_barrier(0);
    // ---- tile boundary: counted wait, then barrier ----
    if (tt < NKT - 2) {
      asm volatile("s_waitcnt vmcnt(4)" ::: "memory");
      __builtin_amdgcn_sched_barrier(0);
      __builtin_amdgcn_s_barrier();
      __builtin_amdgcn_sched_barrier(0);
    } else if (tt == NKT - 2) {
      asm volatile("s_waitcnt vmcnt(0)" ::: "memory");
      __builtin_amdgcn_sched_barrier(0);
      __builtin_amdgcn_s_barrier();
      __builtin_amdgcn_sched_barrier(0);
    }
  }

  // ---- epilogue: exp -> per-row sums ----
  // elem (mi,ni,jj): row = wm*128 + mi*16 + (lane>>4)*4 + jj
  //                  col = n0 + wn*64 + ni*16 + (lane&15)
  float vmask[4];
  const int ccol = n0 + wn * 64 + (lane & 15);
#pragma unroll
  for (int ni = 0; ni < 4; ++ni)
    vmask[ni] = (ccol + ni * 16 < C_CLS) ? 1.0f : 0.0f;
#pragma unroll
  for (int mi = 0; mi < 8; ++mi) {
#pragma unroll
    for (int jj = 0; jj < 4; ++jj) {
      float rs = 0.0f;
#pragma unroll
      for (int ni = 0; ni < 4; ++ni)
        rs += vmask[ni] * __expf(S_SC * acc[mi][ni][jj]);
      rs += __shfl_xor(rs, 1, 64);
      rs += __shfl_xor(rs, 2, 64);
      rs += __shfl_xor(rs, 4, 64);
      rs += __shfl_xor(rs, 8, 64);
      if ((lane & 15) == 0)
        atomicAdd(&rowsum[wm * 128 + mi * 16 + ((lane >> 4) << 2) + jj], rs);
    }
  }
  __syncthreads();
  if (t < BM) atomicAdd(&sums[m0 + t], rowsum[t]);
}

// ---------------- kernel 4: label column + final loss -------------------------
__global__ void k_finalize(const unsigned short* __restrict__ ebf,
                           const unsigned short* __restrict__ pbf,
                           const int* __restrict__ labels,
                           const float* __restrict__ sums,
                           float* __restrict__ out) {
  __shared__ float part[4];
  int wid = threadIdx.x >> 6, lane = threadIdx.x & 63;
  int b = (blockIdx.x << 2) + wid;
  int lab = labels[b];
  const unsigned short* e = ebf + (size_t)b * D_DIM;
  const unsigned short* p = pbf + (size_t)lab * D_DIM;
  float dot = 0.0f;
#pragma unroll
  for (int i = 0; i < 4; ++i) {
    int d = lane * 4 + i;
    dot += bf2f(e[d]) * bf2f(p[d]);
  }
#pragma unroll
  for (int m = 32; m >= 1; m >>= 1) dot += __shfl_xor(dot, m, 64);
  if (lane == 0) {
    float cs = dot;
    float sn = sqrtf(fmaxf(1.0f - cs * cs, EPS_F));
    sn = fminf(fmaxf(sn, EPS_F), 1.0f - EPS_F);
    float phi = cs * COS_M_F - sn * SIN_M_F;
    float sp = S_SC * phi;
    float total = sums[b] - __expf(S_SC * cs) + __expf(sp);
    part[wid] = logf(total) - sp;
  }
  __syncthreads();
  if (threadIdx.x == 0) {
    float s = part[0] + part[1] + part[2] + part[3];
    atomicAdd(out, s * (1.0f / (float)B_ROWS));
  }
}

// ---------------- launcher ----------------------------------------------------
extern "C" void kernel_launch(void* const* d_in, const int* in_sizes, int n_in,
                              void* d_out, int out_size, void* d_ws, size_t ws_size,
                              hipStream_t stream) {
  const float* emb    = (const float*)d_in[0];
  const int*   labels = (const int*)d_in[1];
  const float* proto  = (const float*)d_in[2];
  float* out = (float*)d_out;

  char* ws = (char*)d_ws;
  unsigned short* ebf = (unsigned short*)ws;                 // 524288 B
  float* sums = (float*)(ws + 524288);                       // 4096 B
  unsigned short* pbf = (unsigned short*)(ws + 2097152);     // CPAD*256*2 = 102.5 MB

  hipMemsetAsync(sums, 0, B_ROWS * sizeof(float), stream);
  hipMemsetAsync(out, 0, sizeof(float), stream);

  k_norm_embed<<<B_ROWS / 4, 256, 0, stream>>>(emb, ebf);
  k_proto_norm_cvt<<<CPAD / 4, 256, 0, stream>>>(proto, pbf);
  k_gemm_8ph<<<NBLK, 512, 0, stream>>>(ebf, pbf, sums);
  k_finalize<<<B_ROWS / 4, 256, 0, stream>>>(ebf, pbf, labels, sums, out);
}

// Round 6
// 221.756 us; speedup vs baseline: 1.1239x; 1.1239x over previous
//
#include <hip/hip_runtime.h>
#include <cstdint>
#include <cstddef>

#define D_DIM   256
#define B_ROWS  1024
#define C_CLS   200000
#define S_SC    64.0f
#define COS_M_F 0.87758256189037271612f
#define SIN_M_F 0.47942553860420300027f
#define EPS_F   1e-8f

#define BM 128
#define BN 128
#define BK 64
#define NT 1563                    /* N-tiles: 1563*128 = 200064 >= 200000 */
#define NBLK (8 * NT)              /* 12504 = 8*1563, bijective XCD swizzle */
#define CPAD 200192                /* padded pbf rows (>= 200064), zero-filled */

typedef short bf16x8 __attribute__((ext_vector_type(8)));
typedef float f32x4  __attribute__((ext_vector_type(4)));

__device__ __forceinline__ unsigned short f2bf(float x) {
  unsigned int u = __builtin_bit_cast(unsigned int, x);
  return (unsigned short)((u + 0x8000u) >> 16);
}
__device__ __forceinline__ float bf2f(unsigned short u) {
  return __builtin_bit_cast(float, ((unsigned int)u) << 16);
}

// ------- kernel 1: normalize {prototypes, embeddings} -> bf16 (one pass) ------
// blocks [0, CPAD/4): prototype rows (zero-pad >= C_CLS)
// blocks [CPAD/4, CPAD/4 + B_ROWS/4): embedding rows
__global__ void k_norm_all(const float* __restrict__ emb,
                           const float* __restrict__ proto,
                           unsigned short* __restrict__ ebf,
                           unsigned short* __restrict__ pbf) {
  int wid = threadIdx.x >> 6, lane = threadIdx.x & 63;
  int idx = (blockIdx.x << 2) + wid;
  const float* src;
  unsigned short* dst;
  if (idx < CPAD) {
    if (idx >= C_CLS) {
      *reinterpret_cast<ushort4*>(pbf + (size_t)idx * D_DIM + lane * 4) =
          (ushort4){0, 0, 0, 0};
      return;
    }
    src = proto + (size_t)idx * D_DIM;
    dst = pbf + (size_t)idx * D_DIM;
  } else {
    int row = idx - CPAD;
    src = emb + (size_t)row * D_DIM;
    dst = ebf + (size_t)row * D_DIM;
  }
  const float4 v = *reinterpret_cast<const float4*>(src + lane * 4);
  float ss = v.x * v.x + v.y * v.y + v.z * v.z + v.w * v.w;
#pragma unroll
  for (int m = 32; m >= 1; m >>= 1) ss += __shfl_xor(ss, m, 64);
  float inv = 1.0f / fmaxf(sqrtf(ss), 1e-12f);
  ushort4 o;
  o.x = f2bf(v.x * inv); o.y = f2bf(v.y * inv);
  o.z = f2bf(v.z * inv); o.w = f2bf(v.w * inv);
  *reinterpret_cast<ushort4*>(dst + lane * 4) = o;
}

// ------- kernel 2: fused 128x128 GEMM + exp + row-sum (TLP structure) ---------
// Simple 2-barrier K-loop, 33 KB LDS -> 4 blocks/CU co-resident; the implicit
// wave-level overlap across blocks hides the stage/vmcnt/barrier drain (m114).
__global__ __launch_bounds__(256, 4) void k_gemm_exp(
    const unsigned short* __restrict__ ebf, const unsigned short* __restrict__ pbf,
    float* __restrict__ sums) {
  __shared__ short As[BM * BK];     // 16 KiB, row = 128 B, XOR-swizzled 16B slots
  __shared__ short Bs[BN * BK];     // 16 KiB
  __shared__ float rowsum[BM];

  const int t = threadIdx.x;
  int bid = (int)blockIdx.x;
  int w = (bid & 7) * NT + (bid >> 3);    // bijective: NBLK = 8*NT
  const int ntile = w >> 3;
  const int mtile = w & 7;
  const int m0 = mtile * BM;
  const int n0 = ntile * BN;
  const int lane = t & 63, wid = t >> 6;
  const int wm = wid >> 1, wn = wid & 1;  // 2x2 wave grid, wave tile 64x64

  if (t < BM) rowsum[t] = 0.0f;

  f32x4 acc[4][4];
  const f32x4 fz = {0.0f, 0.0f, 0.0f, 0.0f};
#pragma unroll
  for (int i = 0; i < 4; ++i)
#pragma unroll
    for (int j = 0; j < 4; ++j) acc[i][j] = fz;

  const int srow = t >> 3;       // 0..31  (+ j*32)
  const int sphys = t & 7;       // physical 16B slot

  for (int k0 = 0; k0 < D_DIM; k0 += BK) {
#pragma unroll
    for (int j = 0; j < 4; ++j) {
      int r = j * 32 + srow;
      int sl = sphys ^ (r & 7);
      const unsigned short* gA = ebf + (size_t)(m0 + r) * D_DIM + k0 + sl * 8;
      __builtin_amdgcn_global_load_lds(
          (const __attribute__((address_space(1))) unsigned int*)(const void*)gA,
          (__attribute__((address_space(3))) unsigned int*)(void*)(As + j * 2048 + t * 8),
          16, 0, 0);
      const unsigned short* gB = pbf + (size_t)(n0 + r) * D_DIM + k0 + sl * 8;
      __builtin_amdgcn_global_load_lds(
          (const __attribute__((address_space(1))) unsigned int*)(const void*)gB,
          (__attribute__((address_space(3))) unsigned int*)(void*)(Bs + j * 2048 + t * 8),
          16, 0, 0);
    }
    __syncthreads();

#pragma unroll
    for (int ks = 0; ks < 2; ++ks) {
      bf16x8 af[4], bfr[4];
#pragma unroll
      for (int mi = 0; mi < 4; ++mi) {
        int r = wm * 64 + mi * 16 + (lane & 15);
        int sl = (ks * 4 + (lane >> 4)) ^ (r & 7);
        af[mi] = *reinterpret_cast<const bf16x8*>(As + r * 64 + sl * 8);
      }
#pragma unroll
      for (int ni = 0; ni < 4; ++ni) {
        int r = wn * 64 + ni * 16 + (lane & 15);
        int sl = (ks * 4 + (lane >> 4)) ^ (r & 7);
        bfr[ni] = *reinterpret_cast<const bf16x8*>(Bs + r * 64 + sl * 8);
      }
      __builtin_amdgcn_s_setprio(1);
#pragma unroll
      for (int mi = 0; mi < 4; ++mi)
#pragma unroll
        for (int ni = 0; ni < 4; ++ni)
          acc[mi][ni] = __builtin_amdgcn_mfma_f32_16x16x32_bf16(
              af[mi], bfr[ni], acc[mi][ni], 0, 0, 0);
      __builtin_amdgcn_s_setprio(0);
    }
    __syncthreads();
  }

  // ---- epilogue: exp -> per-row sums (pbf pre-normalized) ----
  // elem (mi,ni,j): row = wm*64+mi*16+(lane>>4)*4+j ; col = n0+wn*64+ni*16+(lane&15)
  float vmask[4];
  const int ccol = n0 + wn * 64 + (lane & 15);
#pragma unroll
  for (int ni = 0; ni < 4; ++ni)
    vmask[ni] = (ccol + ni * 16 < C_CLS) ? 1.0f : 0.0f;
#pragma unroll
  for (int mi = 0; mi < 4; ++mi) {
#pragma unroll
    for (int j = 0; j < 4; ++j) {
      float rs = 0.0f;
#pragma unroll
      for (int ni = 0; ni < 4; ++ni)
        rs += vmask[ni] * __expf(S_SC * acc[mi][ni][j]);
      rs += __shfl_xor(rs, 1, 64);
      rs += __shfl_xor(rs, 2, 64);
      rs += __shfl_xor(rs, 4, 64);
      rs += __shfl_xor(rs, 8, 64);
      if ((lane & 15) == 0)
        atomicAdd(&rowsum[wm * 64 + mi * 16 + ((lane >> 4) << 2) + j], rs);
    }
  }
  __syncthreads();
  if (t < BM) atomicAdd(&sums[m0 + t], rowsum[t]);
}

// ---------------- kernel 3: label column + final loss -------------------------
__global__ void k_finalize(const unsigned short* __restrict__ ebf,
                           const unsigned short* __restrict__ pbf,
                           const int* __restrict__ labels,
                           const float* __restrict__ sums,
                           float* __restrict__ out) {
  __shared__ float part[4];
  int wid = threadIdx.x >> 6, lane = threadIdx.x & 63;
  int b = (blockIdx.x << 2) + wid;
  int lab = labels[b];
  const unsigned short* e = ebf + (size_t)b * D_DIM;
  const unsigned short* p = pbf + (size_t)lab * D_DIM;
  float dot = 0.0f;
#pragma unroll
  for (int i = 0; i < 4; ++i) {
    int d = lane * 4 + i;
    dot += bf2f(e[d]) * bf2f(p[d]);
  }
#pragma unroll
  for (int m = 32; m >= 1; m >>= 1) dot += __shfl_xor(dot, m, 64);
  if (lane == 0) {
    float cs = dot;
    float sn = sqrtf(fmaxf(1.0f - cs * cs, EPS_F));
    sn = fminf(fmaxf(sn, EPS_F), 1.0f - EPS_F);
    float phi = cs * COS_M_F - sn * SIN_M_F;
    float sp = S_SC * phi;
    float total = sums[b] - __expf(S_SC * cs) + __expf(sp);
    part[wid] = logf(total) - sp;
  }
  __syncthreads();
  if (threadIdx.x == 0) {
    float s = part[0] + part[1] + part[2] + part[3];
    atomicAdd(out, s * (1.0f / (float)B_ROWS));
  }
}

// ---------------- launcher ----------------------------------------------------
extern "C" void kernel_launch(void* const* d_in, const int* in_sizes, int n_in,
                              void* d_out, int out_size, void* d_ws, size_t ws_size,
                              hipStream_t stream) {
  const float* emb    = (const float*)d_in[0];
  const int*   labels = (const int*)d_in[1];
  const float* proto  = (const float*)d_in[2];
  float* out = (float*)d_out;

  char* ws = (char*)d_ws;
  unsigned short* ebf = (unsigned short*)ws;                 // 524288 B
  float* sums = (float*)(ws + 524288);                       // 4096 B
  unsigned short* pbf = (unsigned short*)(ws + 2097152);     // CPAD*256*2 = 102.5 MB

  hipMemsetAsync(sums, 0, B_ROWS * sizeof(float), stream);
  hipMemsetAsync(out, 0, sizeof(float), stream);

  k_norm_all<<<(CPAD + B_ROWS) / 4, 256, 0, stream>>>(emb, proto, ebf, pbf);
  k_gemm_exp<<<NBLK, 256, 0, stream>>>(ebf, pbf, sums);
  k_finalize<<<B_ROWS / 4, 256, 0, stream>>>(ebf, pbf, labels, sums, out);
}

// Round 7
// 173.740 us; speedup vs baseline: 1.4345x; 1.2764x over previous
//
#include <hip/hip_runtime.h>
#include <cstdint>
#include <cstddef>

#define D_DIM   256
#define B_ROWS  1024
#define C_CLS   200000
#define S_SC    64.0f
#define COS_M_F 0.87758256189037271612f
#define SIN_M_F 0.47942553860420300027f
#define EPS_F   1e-8f

#define BM 128
#define BN 256
#define BKF 128                    /* fp8 K per step; row = 128 B = one bank sweep */
#define NT 782                     /* N-tiles: 782*256 = 200192 */
#define CPAD (NT * BN)             /* 200192 */
#define NBLK (8 * NT)              /* 6256 = 8*782, bijective XCD swizzle */

typedef float f32x4 __attribute__((ext_vector_type(4)));

// ---------------- kernel 1: normalize {proto, emb} -> fp8 e4m3 ----------------
__global__ void k_norm_all8(const float* __restrict__ emb,
                            const float* __restrict__ proto,
                            unsigned char* __restrict__ ebf8,
                            unsigned char* __restrict__ pbf8) {
  int wid = threadIdx.x >> 6, lane = threadIdx.x & 63;
  int idx = (blockIdx.x << 2) + wid;
  const float* src;
  unsigned char* dst;
  if (idx < CPAD) {
    if (idx >= C_CLS) {
      *reinterpret_cast<unsigned int*>(pbf8 + (size_t)idx * D_DIM + lane * 4) = 0u;
      return;
    }
    src = proto + (size_t)idx * D_DIM;
    dst = pbf8 + (size_t)idx * D_DIM;
  } else {
    int row = idx - CPAD;
    src = emb + (size_t)row * D_DIM;
    dst = ebf8 + (size_t)row * D_DIM;
  }
  const float4 v = *reinterpret_cast<const float4*>(src + lane * 4);
  float ss = v.x * v.x + v.y * v.y + v.z * v.z + v.w * v.w;
#pragma unroll
  for (int m = 32; m >= 1; m >>= 1) ss += __shfl_xor(ss, m, 64);
  float inv = 1.0f / fmaxf(sqrtf(ss), 1e-12f);
  int packed = 0;
  packed = __builtin_amdgcn_cvt_pk_fp8_f32(v.x * inv, v.y * inv, packed, false);
  packed = __builtin_amdgcn_cvt_pk_fp8_f32(v.z * inv, v.w * inv, packed, true);
  *reinterpret_cast<int*>(dst + lane * 4) = packed;
}

// ---------------- kernel 2: fp8 GEMM + exp + row-sum --------------------------
// 128x256 tile, BK=128 (2 K-steps), 8 waves (2Mx4N, 64x64), 2 blocks/CU.
// LDS rows = 128 B; granule XOR swizzle g^=(r&7) keeps both the 16 B
// global_load_lds granules and the b64 fragment reads bank-optimal.
__global__ __launch_bounds__(512, 4) void k_gemm_fp8(
    const unsigned char* __restrict__ ebf8, const unsigned char* __restrict__ pbf8,
    float* __restrict__ sums) {
  __shared__ __align__(16) unsigned char As[BM * BKF];   // 16 KiB
  __shared__ __align__(16) unsigned char Bs[BN * BKF];   // 32 KiB
  __shared__ float rowsum[BM];

  const int t = threadIdx.x;
  const int lane = t & 63;
  const int wm = (t >> 6) >> 2;     // 0..1 : 64-row strip
  const int wn = (t >> 6) & 3;      // 0..3 : 64-col strip

  int bid = (int)blockIdx.x;
  int w = (bid & 7) * NT + (bid >> 3);   // bijective: NBLK = 8*NT
  const int ntile = w >> 3;
  const int mtile = w & 7;
  const int m0 = mtile * BM;
  const int n0 = ntile * BN;

  f32x4 acc[4][4];
  const f32x4 fz = {0.0f, 0.0f, 0.0f, 0.0f};
#pragma unroll
  for (int mi = 0; mi < 4; ++mi)
#pragma unroll
    for (int ni = 0; ni < 4; ++ni) acc[mi][ni] = fz;

  // stage: dest granule G (16 B) linear; source k-granule pre-swizzled by row
  auto stageA = [&](int k0) {
#pragma unroll
    for (int j = 0; j < 2; ++j) {
      int G = j * 512 + t;
      int r = G >> 3, p = G & 7;
      int lg = p ^ (r & 7);
      const unsigned char* g = ebf8 + (size_t)(m0 + r) * D_DIM + k0 + lg * 16;
      __builtin_amdgcn_global_load_lds(
          (const __attribute__((address_space(1))) unsigned int*)(const void*)g,
          (__attribute__((address_space(3))) unsigned int*)(void*)(As + G * 16),
          16, 0, 0);
    }
  };
  auto stageB = [&](int k0) {
#pragma unroll
    for (int j = 0; j < 4; ++j) {
      int G = j * 512 + t;
      int r = G >> 3, p = G & 7;
      int lg = p ^ (r & 7);
      const unsigned char* g = pbf8 + (size_t)(n0 + r) * D_DIM + k0 + lg * 16;
      __builtin_amdgcn_global_load_lds(
          (const __attribute__((address_space(1))) unsigned int*)(const void*)g,
          (__attribute__((address_space(3))) unsigned int*)(void*)(Bs + G * 16),
          16, 0, 0);
    }
  };

  const int q = lane >> 4;   // k-quarter within a 32-k chunk
  auto rdA = [&](int c, int r) -> long {
    int s = 4 * c + q;
    int phys = s ^ ((r & 7) << 1);
    return *reinterpret_cast<const long*>(As + r * BKF + phys * 8);
  };
  auto rdB = [&](int c, int r) -> long {
    int s = 4 * c + q;
    int phys = s ^ ((r & 7) << 1);
    return *reinterpret_cast<const long*>(Bs + r * BKF + phys * 8);
  };

  auto COMPUTE = [&]() {
#pragma unroll
    for (int c = 0; c < 4; ++c) {    // 4 chunks of K=32
      long af[4], bf[4];
#pragma unroll
      for (int mi = 0; mi < 4; ++mi)
        af[mi] = rdA(c, wm * 64 + mi * 16 + (lane & 15));
#pragma unroll
      for (int ni = 0; ni < 4; ++ni)
        bf[ni] = rdB(c, wn * 64 + ni * 16 + (lane & 15));
      __builtin_amdgcn_s_setprio(1);
#pragma unroll
      for (int mi = 0; mi < 4; ++mi)
#pragma unroll
        for (int ni = 0; ni < 4; ++ni)
          acc[mi][ni] = __builtin_amdgcn_mfma_f32_16x16x32_fp8_fp8(
              af[mi], bf[ni], acc[mi][ni], 0, 0, 0);
      __builtin_amdgcn_s_setprio(0);
    }
  };

  // ---- schedule: 2 K-steps, single buffer, TLP (2 blocks/CU) hides drains ----
  stageA(0); stageB(0);
  if (t < BM) rowsum[t] = 0.0f;
  asm volatile("s_waitcnt vmcnt(0)" ::: "memory");
  __syncthreads();
  COMPUTE();
  __syncthreads();
  stageA(BKF); stageB(BKF);
  asm volatile("s_waitcnt vmcnt(0)" ::: "memory");
  __syncthreads();
  COMPUTE();

  // ---- epilogue: exp -> per-row sums ----
  // elem (mi,ni,j): row = wm*64+mi*16+(lane>>4)*4+j ; col = n0+wn*64+ni*16+(lane&15)
  float vmask[4];
  const int ccol = n0 + wn * 64 + (lane & 15);
#pragma unroll
  for (int ni = 0; ni < 4; ++ni)
    vmask[ni] = (ccol + ni * 16 < C_CLS) ? 1.0f : 0.0f;
#pragma unroll
  for (int mi = 0; mi < 4; ++mi) {
#pragma unroll
    for (int j = 0; j < 4; ++j) {
      float rs = 0.0f;
#pragma unroll
      for (int ni = 0; ni < 4; ++ni)
        rs += vmask[ni] * __expf(S_SC * acc[mi][ni][j]);
      rs += __shfl_xor(rs, 1, 64);
      rs += __shfl_xor(rs, 2, 64);
      rs += __shfl_xor(rs, 4, 64);
      rs += __shfl_xor(rs, 8, 64);
      if ((lane & 15) == 0)
        atomicAdd(&rowsum[wm * 64 + mi * 16 + ((lane >> 4) << 2) + j], rs);
    }
  }
  __syncthreads();
  if (t < BM) atomicAdd(&sums[m0 + t], rowsum[t]);
}

// ---------------- kernel 3: label column + final loss -------------------------
__device__ __forceinline__ float f8tof(unsigned char u) {
  int e = (u >> 3) & 15, m = u & 7;
  float mag = e ? ldexpf((float)(8 + m), e - 10) : ldexpf((float)m, -9);
  return (u & 0x80) ? -mag : mag;
}

__global__ void k_finalize(const unsigned char* __restrict__ ebf8,
                           const unsigned char* __restrict__ pbf8,
                           const int* __restrict__ labels,
                           const float* __restrict__ sums,
                           float* __restrict__ out) {
  __shared__ float part[4];
  int wid = threadIdx.x >> 6, lane = threadIdx.x & 63;
  int b = (blockIdx.x << 2) + wid;
  int lab = labels[b];
  const unsigned char* e = ebf8 + (size_t)b * D_DIM + lane * 4;
  const unsigned char* p = pbf8 + (size_t)lab * D_DIM + lane * 4;
  unsigned int eu = *reinterpret_cast<const unsigned int*>(e);
  unsigned int pu = *reinterpret_cast<const unsigned int*>(p);
  float dot = 0.0f;
#pragma unroll
  for (int i = 0; i < 4; ++i)
    dot += f8tof((eu >> (8 * i)) & 0xff) * f8tof((pu >> (8 * i)) & 0xff);
#pragma unroll
  for (int m = 32; m >= 1; m >>= 1) dot += __shfl_xor(dot, m, 64);
  if (lane == 0) {
    float cs = dot;
    float sn = sqrtf(fmaxf(1.0f - cs * cs, EPS_F));
    sn = fminf(fmaxf(sn, EPS_F), 1.0f - EPS_F);
    float phi = cs * COS_M_F - sn * SIN_M_F;
    float sp = S_SC * phi;
    float total = sums[b] - __expf(S_SC * cs) + __expf(sp);
    part[wid] = logf(total) - sp;
  }
  __syncthreads();
  if (threadIdx.x == 0) {
    float s = part[0] + part[1] + part[2] + part[3];
    atomicAdd(out, s * (1.0f / (float)B_ROWS));
  }
}

// ---------------- launcher ----------------------------------------------------
extern "C" void kernel_launch(void* const* d_in, const int* in_sizes, int n_in,
                              void* d_out, int out_size, void* d_ws, size_t ws_size,
                              hipStream_t stream) {
  const float* emb    = (const float*)d_in[0];
  const int*   labels = (const int*)d_in[1];
  const float* proto  = (const float*)d_in[2];
  float* out = (float*)d_out;

  char* ws = (char*)d_ws;
  unsigned char* ebf8 = (unsigned char*)ws;                 // 262144 B
  float* sums = (float*)(ws + 262144);                      // 4096 B
  unsigned char* pbf8 = (unsigned char*)(ws + 2097152);     // CPAD*256 = 51.2 MB

  hipMemsetAsync(sums, 0, B_ROWS * sizeof(float), stream);
  hipMemsetAsync(out, 0, sizeof(float), stream);

  k_norm_all8<<<(CPAD + B_ROWS) / 4, 256, 0, stream>>>(emb, proto, ebf8, pbf8);
  k_gemm_fp8<<<NBLK, 512, 0, stream>>>(ebf8, pbf8, sums);
  k_finalize<<<B_ROWS / 4, 256, 0, stream>>>(ebf8, pbf8, labels, sums, out);
}